// Round 6
// baseline (68.640 us; speedup 1.0000x reference)
//
#include <hip/hip_runtime.h>
#include <math.h>

#define EDIM 128
#define NATOM 128
#define NBATCH 512
#define THREADS 1024
#define ROWLEN 257

typedef __attribute__((ext_vector_type(8))) short bf16x8;           // 8 bf16 (4 VGPRs)
typedef __attribute__((ext_vector_type(4))) float f32x4;            // MFMA C/D frag
typedef __attribute__((ext_vector_type(4))) unsigned short u16x4;   // 8B packed bf16
typedef float f4u __attribute__((ext_vector_type(4), aligned(4)));  // element-aligned float4

__device__ __forceinline__ unsigned short f2bf(float f) {       // RNE float->bf16
    unsigned u = __float_as_uint(f);
    u += 0x7FFFu + ((u >> 16) & 1u);
    return (unsigned short)(u >> 16);
}
__device__ __forceinline__ float bf2f(unsigned short h) {
    return __uint_as_float(((unsigned)h) << 16);
}
__device__ __forceinline__ float fast_ssp(float x) {            // softplus(x)-log2, stable
    return fmaxf(x, 0.f) + __logf(1.f + __expf(-fabsf(x))) - 0.69314718055994531f;
}
// XOR swizzle on a row-major [128][256B] bf16 plane; phase decorrelates X vs K plane.
__device__ __forceinline__ int swzp(int row, int cbyte, int phase) {
    return row * 256 + ((cbyte ^ phase) ^ ((row & 7) << 4));
}

#define PH 0
#define QH 32768
#define PLANE_SZ 65536          // per-batch plane set (act_x/X + act_k/K)

__global__ void wsplit_kernel(const float* __restrict__ Wx,
                              const float* __restrict__ Wk,
                              unsigned short* __restrict__ ws) {
    int g = blockIdx.x * 256 + threadIdx.x;          // 0..32767
    const float* src = (g < 16384) ? Wx : Wk;
    int idx = g & 16383;
    float v = src[idx];
    unsigned short h = f2bf(v);
    unsigned short l = f2bf(v - bf2f(h));
    int base = (g < 16384) ? 0 : 32768;
    ws[base + idx] = h;
    ws[base + 16384 + idx] = l;
}

// ---- phase helpers (barriers live in the caller; all guards are wave-uniform) ----

__device__ __forceinline__ void act_store(char* plane, const f4u v[8], int pi, int pq) {
    const bool isX = (pq < 4);
    char* base = plane + (isX ? PH : QH);
    const int phase = isX ? 0 : 64;
    const int ebase = (pq & 3) * 32;
    #pragma unroll
    for (int j4 = 0; j4 < 8; ++j4) {
        u16x4 hs;
        #pragma unroll
        for (int c = 0; c < 4; ++c) {
            float a = isX ? fast_ssp(v[j4][c]) : fmaxf(v[j4][c], 0.f);
            hs[c] = f2bf(a);
        }
        *(u16x4*)(base + swzp(pi, (ebase + j4 * 4) * 2, phase)) = hs;
    }
}

__device__ __forceinline__ void gemm_mats(const char* plane, const unsigned short* ws,
        const float* bxp, const float* bkp, int wr, int wc, int l15, int l4,
        u16x4 xpk[2][2], u16x4 kpk[2][2], bool nact) {
    if (!nact) return;
    #pragma unroll
    for (int mat = 0; mat < 2; ++mat) {
        const char* act = plane + (mat ? QH : PH);
        const int phase = mat ? 64 : 0;
        const unsigned short* WH = ws + mat * 32768;
        const unsigned short* WL = WH + 16384;
        const float* bias = mat ? bkp : bxp;
        const int n0 = wc * 32;
        f32x4 acc[2][2] = {};
        for (int ks = 0; ks < 4; ++ks) {
            const int e0 = ks * 32 + l4 * 8;
            bf16x8 wh[2], wl[2], ah[2];
            #pragma unroll
            for (int mf = 0; mf < 2; ++mf) {
                int orow = wr * 32 + mf * 16 + l15;
                wh[mf] = *(const bf16x8*)(WH + orow * 128 + e0);
                wl[mf] = *(const bf16x8*)(WL + orow * 128 + e0);
            }
            #pragma unroll
            for (int nf = 0; nf < 2; ++nf) {
                int jrow = n0 + nf * 16 + l15;
                ah[nf] = *(const bf16x8*)(act + swzp(jrow, e0 * 2, phase));
            }
            #pragma unroll
            for (int mf = 0; mf < 2; ++mf)
                #pragma unroll
                for (int nf = 0; nf < 2; ++nf) {
                    acc[mf][nf] = __builtin_amdgcn_mfma_f32_16x16x32_bf16(wh[mf], ah[nf], acc[mf][nf], 0, 0, 0);
                    acc[mf][nf] = __builtin_amdgcn_mfma_f32_16x16x32_bf16(wl[mf], ah[nf], acc[mf][nf], 0, 0, 0);
                }
        }
        #pragma unroll
        for (int mf = 0; mf < 2; ++mf) {
            int ob = wr * 32 + mf * 16 + l4 * 4;
            f32x4 b4 = *(const f32x4*)(bias + ob);
            #pragma unroll
            for (int nf = 0; nf < 2; ++nf) {
                u16x4 hs;
                #pragma unroll
                for (int r = 0; r < 4; ++r) hs[r] = f2bf(acc[mf][nf][r] + b4[r]);
                if (mat) kpk[mf][nf] = hs; else xpk[mf][nf] = hs;
            }
        }
    }
}

__device__ __forceinline__ void write_xk(char* plane, int wr, int wc, int l15, int l4,
        const u16x4 xpk[2][2], const u16x4 kpk[2][2], bool nact) {
    if (!nact) return;
    const int n0 = wc * 32;
    #pragma unroll
    for (int mf = 0; mf < 2; ++mf) {
        int ob2 = (wr * 32 + mf * 16 + l4 * 4) * 2;
        #pragma unroll
        for (int nf = 0; nf < 2; ++nf) {
            int jrow = n0 + nf * 16 + l15;
            *(u16x4*)(plane + PH + swzp(jrow, ob2, 0))  = xpk[mf][nf];
            *(u16x4*)(plane + QH + swzp(jrow, ob2, 64)) = kpk[mf][nf];
        }
    }
}

__device__ __forceinline__ void gram_epi(const char* plane, const float* pX, const float* pY,
        const float* pZ, float* amB, int wr, int wc, int l15, int l4, int count) {
    const int m0g = wr * 32;
    const int n0g = wc * 32;
    if (m0g >= count || n0g >= count) return;
    f32x4 gx[2][2] = {}, gk[2][2] = {};
    for (int ks = 0; ks < 4; ++ks) {           // X gram
        const int e0b = (ks * 32 + l4 * 8) * 2;
        bf16x8 aH[2], bH[2];
        #pragma unroll
        for (int mf = 0; mf < 2; ++mf)
            aH[mf] = *(const bf16x8*)(plane + PH + swzp(m0g + mf * 16 + l15, e0b, 0));
        #pragma unroll
        for (int nf = 0; nf < 2; ++nf)
            bH[nf] = *(const bf16x8*)(plane + PH + swzp(n0g + nf * 16 + l15, e0b, 0));
        #pragma unroll
        for (int mf = 0; mf < 2; ++mf)
            #pragma unroll
            for (int nf = 0; nf < 2; ++nf)
                gx[mf][nf] = __builtin_amdgcn_mfma_f32_16x16x32_bf16(aH[mf], bH[nf], gx[mf][nf], 0, 0, 0);
    }
    for (int ks = 0; ks < 4; ++ks) {           // K gram
        const int e0b = (ks * 32 + l4 * 8) * 2;
        bf16x8 aH[2], bH[2];
        #pragma unroll
        for (int mf = 0; mf < 2; ++mf)
            aH[mf] = *(const bf16x8*)(plane + QH + swzp(m0g + mf * 16 + l15, e0b, 64));
        #pragma unroll
        for (int nf = 0; nf < 2; ++nf)
            bH[nf] = *(const bf16x8*)(plane + QH + swzp(n0g + nf * 16 + l15, e0b, 64));
        #pragma unroll
        for (int mf = 0; mf < 2; ++mf)
            #pragma unroll
            for (int nf = 0; nf < 2; ++nf)
                gk[mf][nf] = __builtin_amdgcn_mfma_f32_16x16x32_bf16(aH[mf], bH[nf], gk[mf][nf], 0, 0, 0);
    }
    const float inv_e = 0.08838834764831845f;            // 1/sqrt(128)
    #pragma unroll
    for (int nf = 0; nf < 2; ++nf) {
        const int j = n0g + nf * 16 + l15;
        const bool jvalid = (j < count);
        const float pjx = pX[j], pjy = pY[j], pjz = pZ[j];
        float amx = 0.f, amy = 0.f, amz = 0.f;
        #pragma unroll
        for (int mf = 0; mf < 2; ++mf) {
            #pragma unroll
            for (int r = 0; r < 4; ++r) {
                const int i = m0g + mf * 16 + l4 * 4 + r;
                float dx = pjx - pX[i];
                float dy = pjy - pY[i];
                float dz = pjz - pZ[i];
                float r2 = fmaf(dx, dx, fmaf(dy, dy, dz * dz)) + 1e-16f;
                float rr = sqrtf(r2);
                bool ok = jvalid && (i < count) && (rr < 5.0f);
                float fc = ok ? (0.5f * (__cosf(rr * 0.62831853071795865f) + 1.f)) : 0.f;
                float xs = fmaf(gx[mf][nf][r], -0.044194173824159216f, rr * 0.5f);
                float fv = xs * (gk[mf][nf][r] * inv_e) * fc;
                float wgt = fv / (rr + 1e-8f);
                amx = fmaf(dx, wgt, amx);
                amy = fmaf(dy, wgt, amy);
                amz = fmaf(dz, wgt, amz);
            }
        }
        amx += __shfl_xor(amx, 16); amx += __shfl_xor(amx, 32);
        amy += __shfl_xor(amy, 16); amy += __shfl_xor(amy, 32);
        amz += __shfl_xor(amz, 16); amz += __shfl_xor(amz, 32);
        if (l4 == 0 && jvalid) {
            atomicAdd(&amB[j * 3 + 0], amx);
            atomicAdd(&amB[j * 3 + 1], amy);
            atomicAdd(&amB[j * 3 + 2], amz);
        }
    }
}

__global__ void __launch_bounds__(THREADS, 4)   // 4 waves/EU: VGPR cap 128, no spill
gen_actions_kernel(const float* __restrict__ kx,
                   const float* __restrict__ pos,
                   const float* __restrict__ mask,
                   const float* __restrict__ scale_ptr,
                   const float* __restrict__ evala,
                   const float* __restrict__ bx,
                   const float* __restrict__ bk,
                   const unsigned short* __restrict__ ws,
                   float* __restrict__ out)
{
    extern __shared__ char lds[];
    __shared__ float posXs[2 * NATOM], posYs[2 * NATOM], posZs[2 * NATOM];
    __shared__ float lsBs[2 * NATOM];
    __shared__ float amBs[2 * NATOM * 3];
    __shared__ float redBs[4];
    __shared__ int   cntBs[4];

    const int bA = blockIdx.x * 2;
    const int bB = bA + 1;
    const int t = threadIdx.x;
    const int lane = t & 63;
    const int w = t >> 6;            // wave 0..15
    const int wr = w >> 2;           // M tile, 0..3
    const int wc = w & 3;            // N tile, 0..3
    const int l15 = lane & 15;
    const int l4  = lane >> 4;
    char* planeA = lds;
    char* planeB = lds + PLANE_SZ;

    // ---- entry: issue BOTH batches' kx loads immediately (A first).
    const int pi = t >> 3, pq = t & 7;
    const float* prowA = kx + (size_t)bA * (NATOM * ROWLEN) + pi * ROWLEN + pq * 32;
    const float* prowB = kx + (size_t)bB * (NATOM * ROWLEN) + pi * ROWLEN + pq * 32;
    f4u vA[8], vB[8];
    #pragma unroll
    for (int j4 = 0; j4 < 8; ++j4) vA[j4] = *(const f4u*)(prowA + j4 * 4);
    #pragma unroll
    for (int j4 = 0; j4 < 8; ++j4) vB[j4] = *(const f4u*)(prowB + j4 * 4);
    float lstdA = (pq == 7) ? prowA[32] : 0.f;
    float lstdB = (pq == 7) ? prowB[32] : 0.f;

    // ---- P1 (overlaps loads): masks/counts/positions for A (waves 0-1) and B (waves 2-3)
    if (t < 2 * NATOM) {
        const int r = t & 127;
        const int bb = (t < NATOM) ? bA : bB;
        float m = mask[bb * NATOM + r];
        unsigned long long bal = __ballot(m > 0.5f);
        if (lane == 0) cntBs[w] = __popcll(bal);
        const float* p = pos + ((size_t)bb * NATOM + r) * 3;
        posXs[t] = p[0]; posYs[t] = p[1]; posZs[t] = p[2];
    }
    if (t < 2 * NATOM * 3) amBs[t] = 0.f;

    // ---- P2A: batch-A activations -> planeA (consumes vA; vB stays in flight)
    act_store(planeA, vA, pi, pq);
    if (pq == 7) { lsBs[pi] = lstdA; lsBs[NATOM + pi] = lstdB; }
    __syncthreads();                                   // B1
    const int countA = cntBs[0] + cntBs[1];
    const int countB = cntBs[2] + cntBs[3];
    const bool nactA = (wc * 32 < countA);
    const bool nactB = (wc * 32 < countB);

    // ---- P3A: GEMM A (MFMA; B's kx loads land underneath)
    u16x4 xpkA[2][2], kpkA[2][2];
    gemm_mats(planeA, ws, bx, bk, wr, wc, l15, l4, xpkA, kpkA, nactA);
    __syncthreads();                                   // B2: planeA act reads done
    write_xk(planeA, wr, wc, l15, l4, xpkA, kpkA, nactA);
    // ---- P2B: batch-B activations -> planeB (consumes vB)
    act_store(planeB, vB, pi, pq);
    __syncthreads();                                   // B3: XA/KA + actB ready

    // ---- P4A grams+epilogue  then  P3B GEMM (same phase, mixed pipes)
    gram_epi(planeA, posXs, posYs, posZs, amBs, wr, wc, l15, l4, countA);
    u16x4 xpkB[2][2], kpkB[2][2];
    gemm_mats(planeB, ws, bx, bk, wr, wc, l15, l4, xpkB, kpkB, nactB);
    __syncthreads();                                   // B4: amA final, actB reads done
    write_xk(planeB, wr, wc, l15, l4, xpkB, kpkB, nactB);

    // ---- P5A part 1: actions-A out + logprob-A reduce (overlaps XB/KB writes)
    if (t < 96) {
        f32x4 ev4 = *(const f32x4*)(evala + (size_t)bA * 384 + t * 4);
        f32x4 o4;
        #pragma unroll
        for (int c = 0; c < 4; ++c) o4[c] = ((t * 4 + c) / 3 < countA) ? ev4[c] : 0.f;
        *(f32x4*)(out + (size_t)bA * 384 + t * 4) = o4;
    }
    {
        float lp = 0.f;
        if (t < NATOM && t < countA) {
            const float* ev = evala + ((size_t)bA * NATOM + t) * 3;
            float e0v = ev[0], e1v = ev[1], e2v = ev[2];
            float scale = scale_ptr[0];
            float ax = amBs[t * 3 + 0], ay = amBs[t * 3 + 1], az = amBs[t * 3 + 2];
            float nrm = sqrtf(fmaf(ax, ax, fmaf(ay, ay, az * az)) + 1e-16f) + 1e-8f;
            float qe = __expf(-2.f * nrm);
            float th = (1.f - qe) / (1.f + qe);
            float sc = th / nrm * scale;
            float ls = fminf(fmaxf(lsBs[t], -20.f), 2.f);
            float sig = __expf(ls) * scale;
            float sinv = 1.f / sig;
            float zx = (e0v - ax * sc) * sinv;
            float zy = (e1v - ay * sc) * sinv;
            float zz = (e2v - az * sc) * sinv;
            lp = -0.5f * (zx * zx + zy * zy + zz * zz) - 3.f * __logf(sig)
                 - 3.f * 0.91893853320467274f;
        }
        #pragma unroll
        for (int off = 32; off > 0; off >>= 1) lp += __shfl_down(lp, off);
        if (t == 0)  redBs[0] = lp;
        if (t == 64) redBs[1] = lp;
    }
    __syncthreads();                                   // B5: XB/KB + redA ready

    // ---- P4B grams+epilogue; logprob-A final write rides along
    gram_epi(planeB, posXs + NATOM, posYs + NATOM, posZs + NATOM,
             amBs + NATOM * 3, wr, wc, l15, l4, countB);
    if (t == 0) out[(size_t)NBATCH * NATOM * 3 + bA] = redBs[0] + redBs[1];
    __syncthreads();                                   // B6: amB final

    // ---- P5B: actions-B out + logprob-B
    if (t < 96) {
        f32x4 ev4 = *(const f32x4*)(evala + (size_t)bB * 384 + t * 4);
        f32x4 o4;
        #pragma unroll
        for (int c = 0; c < 4; ++c) o4[c] = ((t * 4 + c) / 3 < countB) ? ev4[c] : 0.f;
        *(f32x4*)(out + (size_t)bB * 384 + t * 4) = o4;
    }
    {
        float lp = 0.f;
        if (t < NATOM && t < countB) {
            const float* ev = evala + ((size_t)bB * NATOM + t) * 3;
            float e0v = ev[0], e1v = ev[1], e2v = ev[2];
            float scale = scale_ptr[0];
            float ax = amBs[NATOM * 3 + t * 3 + 0];
            float ay = amBs[NATOM * 3 + t * 3 + 1];
            float az = amBs[NATOM * 3 + t * 3 + 2];
            float nrm = sqrtf(fmaf(ax, ax, fmaf(ay, ay, az * az)) + 1e-16f) + 1e-8f;
            float qe = __expf(-2.f * nrm);
            float th = (1.f - qe) / (1.f + qe);
            float sc = th / nrm * scale;
            float ls = fminf(fmaxf(lsBs[NATOM + t], -20.f), 2.f);
            float sig = __expf(ls) * scale;
            float sinv = 1.f / sig;
            float zx = (e0v - ax * sc) * sinv;
            float zy = (e1v - ay * sc) * sinv;
            float zz = (e2v - az * sc) * sinv;
            lp = -0.5f * (zx * zx + zy * zy + zz * zz) - 3.f * __logf(sig)
                 - 3.f * 0.91893853320467274f;
        }
        #pragma unroll
        for (int off = 32; off > 0; off >>= 1) lp += __shfl_down(lp, off);
        if (t == 0)  redBs[2] = lp;
        if (t == 64) redBs[3] = lp;
    }
    __syncthreads();                                   // B7
    if (t == 0) out[(size_t)NBATCH * NATOM * 3 + bB] = redBs[2] + redBs[3];
}

extern "C" void kernel_launch(void* const* d_in, const int* in_sizes, int n_in,
                              void* d_out, int out_size, void* d_ws, size_t ws_size,
                              hipStream_t stream) {
    const float* kx    = (const float*)d_in[0];
    const float* pos   = (const float*)d_in[1];
    const float* mask  = (const float*)d_in[2];
    const float* scale = (const float*)d_in[3];
    const float* ev    = (const float*)d_in[4];
    const float* Wx    = (const float*)d_in[5];
    const float* bx    = (const float*)d_in[6];
    const float* Wk    = (const float*)d_in[7];
    const float* bk    = (const float*)d_in[8];
    float* out = (float*)d_out;
    unsigned short* ws = (unsigned short*)d_ws;

    // W hi/lo split (128KB in d_ws), recomputed each launch (deterministic)
    hipLaunchKernelGGL(wsplit_kernel, dim3(128), dim3(256), 0, stream, Wx, Wk, ws);

    const size_t shbytes = 2 * PLANE_SZ;   // 128KB dynamic: two batch plane-sets
    (void)hipFuncSetAttribute((const void*)gen_actions_kernel,
                              hipFuncAttributeMaxDynamicSharedMemorySize,
                              (int)shbytes);
    hipLaunchKernelGGL(gen_actions_kernel, dim3(NBATCH / 2), dim3(THREADS), shbytes, stream,
                       kx, pos, mask, scale, ev, bx, bk, ws, out);
}